// Round 1
// baseline (2234.763 us; speedup 1.0000x reference)
//
#include <hip/hip_runtime.h>

#define BSZ 4
#define TSEQ 4096
#define DM 1024
#define NH 16
#define HD 64

// ---------------------------------------------------------------------------
// Kernel 1: per (b,h): kh = kv@Wk[h]+bk, vh = kv@Wv[h]+bv; kh2 = kh*kh;
//           kv_sum[b,h,d,e] += sum_t kh2[t,d]*vh[t,e]; ksum[b,h,d] += sum_t kh2[t,d]
// Block: 256 threads, processes 256 t-rows (4 sub-tiles of 64), atomics at end.
// ---------------------------------------------------------------------------
__global__ __launch_bounds__(256) void kv_stats_kernel(
    const float* __restrict__ kv,
    const float* __restrict__ Wk, const float* __restrict__ bk,
    const float* __restrict__ Wv, const float* __restrict__ bv,
    float* __restrict__ kv_sum, float* __restrict__ ksum)
{
    const int tid = threadIdx.x;
    const int tx = tid & 15;
    const int ty = tid >> 4;
    const int b = blockIdx.z;
    const int h = blockIdx.y;
    const int t_base = blockIdx.x * 256;

    __shared__ __align__(16) float As[16][64];
    __shared__ __align__(16) float Bks[16][64];
    __shared__ __align__(16) float Bvs[16][64];
    __shared__ __align__(16) float khs[64][64];
    __shared__ __align__(16) float vhs[64][64];
    __shared__ float bk_s[64];
    __shared__ float bv_s[64];

    if (tid < 64) {
        bk_s[tid] = bk[h * HD + tid];
        bv_s[tid] = bv[h * HD + tid];
    }

    const float* __restrict__ Wkh = Wk + (size_t)h * DM * HD;
    const float* __restrict__ Wvh = Wv + (size_t)h * DM * HD;

    float acc_kv[4][4];
    float acc_ks[4];
    #pragma unroll
    for (int i = 0; i < 4; ++i) {
        acc_ks[i] = 0.f;
        #pragma unroll
        for (int j = 0; j < 4; ++j) acc_kv[i][j] = 0.f;
    }

    const int a_m = tid >> 2;          // 0..63
    const int a_k = (tid & 3) * 4;     // 0,4,8,12
    const int b_k = tid >> 4;          // 0..15
    const int b_c = (tid & 15) * 4;    // 0..60

    for (int sub = 0; sub < 4; ++sub) {
        const int t0 = t_base + sub * 64;
        float ck[4][4] = {};
        float cv[4][4] = {};
        for (int k0 = 0; k0 < DM; k0 += 16) {
            // Stage A (transposed: As[k][m]) and B (direct: Bs[k][n])
            float4 a4 = *(const float4*)&kv[((size_t)b * TSEQ + t0 + a_m) * DM + k0 + a_k];
            As[a_k + 0][a_m] = a4.x;
            As[a_k + 1][a_m] = a4.y;
            As[a_k + 2][a_m] = a4.z;
            As[a_k + 3][a_m] = a4.w;
            *(float4*)&Bks[b_k][b_c] = *(const float4*)&Wkh[(size_t)(k0 + b_k) * HD + b_c];
            *(float4*)&Bvs[b_k][b_c] = *(const float4*)&Wvh[(size_t)(k0 + b_k) * HD + b_c];
            __syncthreads();
            #pragma unroll
            for (int k = 0; k < 16; ++k) {
                float4 av  = *(const float4*)&As[k][ty * 4];
                float4 bkv = *(const float4*)&Bks[k][tx * 4];
                float4 bvv = *(const float4*)&Bvs[k][tx * 4];
                float aa[4] = {av.x, av.y, av.z, av.w};
                float bb[4] = {bkv.x, bkv.y, bkv.z, bkv.w};
                float vv[4] = {bvv.x, bvv.y, bvv.z, bvv.w};
                #pragma unroll
                for (int i = 0; i < 4; ++i)
                    #pragma unroll
                    for (int j = 0; j < 4; ++j) {
                        ck[i][j] = fmaf(aa[i], bb[j], ck[i][j]);
                        cv[i][j] = fmaf(aa[i], vv[j], cv[i][j]);
                    }
            }
            __syncthreads();
        }
        // Epilogue: bias, square kh; park tiles in LDS for the local reduction.
        #pragma unroll
        for (int i = 0; i < 4; ++i)
            #pragma unroll
            for (int j = 0; j < 4; ++j) {
                float kk = ck[i][j] + bk_s[tx * 4 + j];
                khs[ty * 4 + i][tx * 4 + j] = kk * kk;
                vhs[ty * 4 + i][tx * 4 + j] = cv[i][j] + bv_s[tx * 4 + j];
            }
        __syncthreads();
        // Local rank-64 update: acc_kv[d,e] += sum_t kh2[t,d]*vh[t,e]
        #pragma unroll 4
        for (int t = 0; t < 64; ++t) {
            float4 kd = *(const float4*)&khs[t][ty * 4];
            float4 ve = *(const float4*)&vhs[t][tx * 4];
            float kda[4] = {kd.x, kd.y, kd.z, kd.w};
            float vea[4] = {ve.x, ve.y, ve.z, ve.w};
            #pragma unroll
            for (int i = 0; i < 4; ++i) {
                acc_ks[i] += kda[i];
                #pragma unroll
                for (int j = 0; j < 4; ++j)
                    acc_kv[i][j] = fmaf(kda[i], vea[j], acc_kv[i][j]);
            }
        }
        __syncthreads();
    }

    float* kvp = kv_sum + ((size_t)(b * NH + h)) * HD * HD;
    #pragma unroll
    for (int i = 0; i < 4; ++i)
        #pragma unroll
        for (int j = 0; j < 4; ++j)
            atomicAdd(&kvp[(ty * 4 + i) * HD + tx * 4 + j], acc_kv[i][j]);
    if (tx == 0) {
        float* ksp = ksum + (b * NH + h) * HD;
        #pragma unroll
        for (int i = 0; i < 4; ++i)
            atomicAdd(&ksp[ty * 4 + i], acc_ks[i]);  // same value across tx; only tx==0 commits
    }
}

// ---------------------------------------------------------------------------
// Kernel 2: qh = q@Wq[h]+bq; qh2 = qh*qh; z = 1/(qh2 . ksum + 1e-6);
//           attn[b,t,h*64+e] = z * sum_d qh2[t,d]*kv_sum[b,h,d,e]
// Block: 256 threads, one (b, h, 64-row t-tile).
// ---------------------------------------------------------------------------
__global__ __launch_bounds__(256) void q_attn_kernel(
    const float* __restrict__ q,
    const float* __restrict__ Wq, const float* __restrict__ bq,
    const float* __restrict__ kv_sum, const float* __restrict__ ksum,
    float* __restrict__ attn)
{
    const int tid = threadIdx.x;
    const int tx = tid & 15;
    const int ty = tid >> 4;
    const int b = blockIdx.z;
    const int h = blockIdx.y;
    const int t0 = blockIdx.x * 64;

    __shared__ __align__(16) float As[16][64];
    __shared__ __align__(16) float Bs[16][64];
    __shared__ __align__(16) float qs[64][68];   // stride 68: 2-way-max conflicts, 16B-aligned rows
    __shared__ __align__(16) float kvs[64][64];
    __shared__ float ks_s[64];
    __shared__ float bq_s[64];

    // Stage kv_sum (64x64) and ksum/bias for this (b,h).
    const float* __restrict__ kvp = kv_sum + ((size_t)(b * NH + h)) * HD * HD;
    #pragma unroll
    for (int r = 0; r < 4; ++r) {
        int idx = r * 256 + tid;
        *(float4*)((float*)kvs + idx * 4) = *(const float4*)(kvp + idx * 4);
    }
    if (tid < 64) {
        ks_s[tid] = ksum[(b * NH + h) * HD + tid];
        bq_s[tid] = bq[h * HD + tid];
    }

    const float* __restrict__ Wqh = Wq + (size_t)h * DM * HD;
    const int a_m = tid >> 2;
    const int a_k = (tid & 3) * 4;
    const int b_k = tid >> 4;
    const int b_c = (tid & 15) * 4;

    float c[4][4] = {};
    for (int k0 = 0; k0 < DM; k0 += 16) {
        float4 a4 = *(const float4*)&q[((size_t)b * TSEQ + t0 + a_m) * DM + k0 + a_k];
        As[a_k + 0][a_m] = a4.x;
        As[a_k + 1][a_m] = a4.y;
        As[a_k + 2][a_m] = a4.z;
        As[a_k + 3][a_m] = a4.w;
        *(float4*)&Bs[b_k][b_c] = *(const float4*)&Wqh[(size_t)(k0 + b_k) * HD + b_c];
        __syncthreads();
        #pragma unroll
        for (int k = 0; k < 16; ++k) {
            float4 av = *(const float4*)&As[k][ty * 4];
            float4 bv4 = *(const float4*)&Bs[k][tx * 4];
            float aa[4] = {av.x, av.y, av.z, av.w};
            float bb[4] = {bv4.x, bv4.y, bv4.z, bv4.w};
            #pragma unroll
            for (int i = 0; i < 4; ++i)
                #pragma unroll
                for (int j = 0; j < 4; ++j)
                    c[i][j] = fmaf(aa[i], bb[j], c[i][j]);
        }
        __syncthreads();
    }

    // Epilogue: bias + square; park in LDS; z via in-wave reduce over tx (16 consecutive lanes).
    float qh2r[4][4];
    #pragma unroll
    for (int i = 0; i < 4; ++i)
        #pragma unroll
        for (int j = 0; j < 4; ++j) {
            float v = c[i][j] + bq_s[tx * 4 + j];
            v = v * v;
            qh2r[i][j] = v;
            qs[ty * 4 + i][tx * 4 + j] = v;
        }
    float zr[4];
    #pragma unroll
    for (int i = 0; i < 4; ++i) {
        float p = qh2r[i][0] * ks_s[tx * 4 + 0] + qh2r[i][1] * ks_s[tx * 4 + 1]
                + qh2r[i][2] * ks_s[tx * 4 + 2] + qh2r[i][3] * ks_s[tx * 4 + 3];
        p += __shfl_xor(p, 1);
        p += __shfl_xor(p, 2);
        p += __shfl_xor(p, 4);
        p += __shfl_xor(p, 8);
        zr[i] = 1.f / (p + 1e-6f);
    }
    __syncthreads();

    // attn tile: s[t,e] = sum_d qh2[t,d]*kvs[d,e]
    float s[4][4] = {};
    #pragma unroll 4
    for (int d4 = 0; d4 < 64; d4 += 4) {
        float4 ar[4], br[4];
        #pragma unroll
        for (int i = 0; i < 4; ++i) ar[i] = *(const float4*)&qs[ty * 4 + i][d4];
        #pragma unroll
        for (int r = 0; r < 4; ++r) br[r] = *(const float4*)&kvs[d4 + r][tx * 4];
        float brr[4][4] = {{br[0].x, br[0].y, br[0].z, br[0].w},
                           {br[1].x, br[1].y, br[1].z, br[1].w},
                           {br[2].x, br[2].y, br[2].z, br[2].w},
                           {br[3].x, br[3].y, br[3].z, br[3].w}};
        #pragma unroll
        for (int i = 0; i < 4; ++i) {
            float ai[4] = {ar[i].x, ar[i].y, ar[i].z, ar[i].w};
            #pragma unroll
            for (int r = 0; r < 4; ++r)
                #pragma unroll
                for (int j = 0; j < 4; ++j)
                    s[i][j] = fmaf(ai[r], brr[r][j], s[i][j]);
        }
    }

    #pragma unroll
    for (int i = 0; i < 4; ++i) {
        float4 o;
        o.x = s[i][0] * zr[i];
        o.y = s[i][1] * zr[i];
        o.z = s[i][2] * zr[i];
        o.w = s[i][3] * zr[i];
        *(float4*)&attn[((size_t)b * TSEQ + t0 + ty * 4 + i) * DM + h * HD + tx * 4] = o;
    }
}

// ---------------------------------------------------------------------------
// Kernel 3: out = attn @ Wo^T + bo.  Standard 64x64 tile GEMM, BK=16.
// ---------------------------------------------------------------------------
__global__ __launch_bounds__(256) void out_proj_kernel(
    const float* __restrict__ attn, const float* __restrict__ Wo,
    const float* __restrict__ bo, float* __restrict__ out)
{
    const int tid = threadIdx.x;
    const int tx = tid & 15;
    const int ty = tid >> 4;
    const int n0 = blockIdx.x * 64;
    const size_t m0 = (size_t)blockIdx.y * 64;

    __shared__ __align__(16) float As[16][64];
    __shared__ __align__(16) float Bs[16][64];
    __shared__ float bo_s[64];
    if (tid < 64) bo_s[tid] = bo[n0 + tid];

    const int a_m = tid >> 2;
    const int a_k = (tid & 3) * 4;

    float c[4][4] = {};
    for (int k0 = 0; k0 < DM; k0 += 16) {
        float4 a4 = *(const float4*)&attn[(m0 + a_m) * DM + k0 + a_k];
        As[a_k + 0][a_m] = a4.x;
        As[a_k + 1][a_m] = a4.y;
        As[a_k + 2][a_m] = a4.z;
        As[a_k + 3][a_m] = a4.w;
        float4 b4 = *(const float4*)&Wo[(size_t)(n0 + a_m) * DM + k0 + a_k];  // Bs[k][n] = Wo[n][k]
        Bs[a_k + 0][a_m] = b4.x;
        Bs[a_k + 1][a_m] = b4.y;
        Bs[a_k + 2][a_m] = b4.z;
        Bs[a_k + 3][a_m] = b4.w;
        __syncthreads();
        #pragma unroll
        for (int k = 0; k < 16; ++k) {
            float4 av = *(const float4*)&As[k][ty * 4];
            float4 bv4 = *(const float4*)&Bs[k][tx * 4];
            float aa[4] = {av.x, av.y, av.z, av.w};
            float bb[4] = {bv4.x, bv4.y, bv4.z, bv4.w};
            #pragma unroll
            for (int i = 0; i < 4; ++i)
                #pragma unroll
                for (int j = 0; j < 4; ++j)
                    c[i][j] = fmaf(aa[i], bb[j], c[i][j]);
        }
        __syncthreads();
    }

    #pragma unroll
    for (int i = 0; i < 4; ++i) {
        float4 o;
        o.x = c[i][0] + bo_s[tx * 4 + 0];
        o.y = c[i][1] + bo_s[tx * 4 + 1];
        o.z = c[i][2] + bo_s[tx * 4 + 2];
        o.w = c[i][3] + bo_s[tx * 4 + 3];
        *(float4*)&out[(m0 + ty * 4 + i) * DM + n0 + tx * 4] = o;
    }
}

// ---------------------------------------------------------------------------
extern "C" void kernel_launch(void* const* d_in, const int* in_sizes, int n_in,
                              void* d_out, int out_size, void* d_ws, size_t ws_size,
                              hipStream_t stream) {
    const float* q  = (const float*)d_in[0];
    const float* kv = (const float*)d_in[1];
    const float* Wq = (const float*)d_in[2];
    const float* bq = (const float*)d_in[3];
    const float* Wk = (const float*)d_in[4];
    const float* bk = (const float*)d_in[5];
    const float* Wv = (const float*)d_in[6];
    const float* bv = (const float*)d_in[7];
    const float* Wo = (const float*)d_in[8];
    const float* bo = (const float*)d_in[9];
    float* out = (float*)d_out;

    float* kv_sum = (float*)d_ws;                          // [B,H,64,64] = 262144 floats
    float* ksum   = kv_sum + (size_t)BSZ * NH * HD * HD;   // [B,H,64]    = 4096 floats
    float* attn   = ksum + (size_t)BSZ * NH * HD;          // [B*T,1024]  = 16.7M floats

    // zero the accumulation buffers (ws is poisoned 0xAA before every call)
    size_t zero_bytes = ((size_t)BSZ * NH * HD * HD + (size_t)BSZ * NH * HD) * sizeof(float);
    hipMemsetAsync(d_ws, 0, zero_bytes, stream);

    kv_stats_kernel<<<dim3(TSEQ / 256, NH, BSZ), 256, 0, stream>>>(
        kv, Wk, bk, Wv, bv, kv_sum, ksum);
    q_attn_kernel<<<dim3(TSEQ / 64, NH, BSZ), 256, 0, stream>>>(
        q, Wq, bq, kv_sum, ksum, attn);
    out_proj_kernel<<<dim3(DM / 64, (BSZ * TSEQ) / 64), 256, 0, stream>>>(
        attn, Wo, bo, out);
}

// Round 4
// 1158.867 us; speedup vs baseline: 1.9284x; 1.9284x over previous
//
#include <hip/hip_runtime.h>

#define BSZ 4
#define TSEQ 4096
#define DM 1024
#define NH 16
#define HD 64
#define BT (BSZ * TSEQ)
#define LDH 40            // padded f16 row stride for 32-wide K-tiles (80 B): 2-way max conflicts
#define INV_LOSCALE (1.0f / 4096.0f)

using f32x4 = __attribute__((ext_vector_type(4))) float;
using f16x8 = __attribute__((ext_vector_type(8))) _Float16;
using u32x2 = __attribute__((ext_vector_type(2))) unsigned;
using u32x4 = __attribute__((ext_vector_type(4))) unsigned;

// f16 RTN split: x = hi + lo/4096 + r, |r| <= 2^-24|x|. lo stored pre-scaled by
// 4096 so it never lands in f16-denormal range (MFMA/cvt flush immunity).
__device__ __forceinline__ void split1(float x, _Float16& h, _Float16& l) {
    h = (_Float16)x;
    l = (_Float16)((x - (float)h) * 4096.0f);
}
__device__ __forceinline__ unsigned pack2(_Float16 a, _Float16 b) {
    return (unsigned)__builtin_bit_cast(unsigned short, a) |
           ((unsigned)__builtin_bit_cast(unsigned short, b) << 16);
}
__device__ __forceinline__ f32x4 mfma_f16(f16x8 a, f16x8 b, f32x4 c) {
    return __builtin_amdgcn_mfma_f32_16x16x32_f16(a, b, c, 0, 0, 0);
}

// ---------------------------------------------------------------------------
// Elementwise fp32 -> f16 hi/lo split (kv, Wo).
// ---------------------------------------------------------------------------
__global__ __launch_bounds__(256) void split_kernel(const float* __restrict__ in,
        _Float16* __restrict__ hi, _Float16* __restrict__ lo, int n4) {
    int i = blockIdx.x * 256 + threadIdx.x;
    if (i >= n4) return;
    f32x4 v = ((const f32x4*)in)[i];
    _Float16 h[4], l[4];
    #pragma unroll
    for (int j = 0; j < 4; ++j) split1(v[j], h[j], l[j]);
    ((u32x2*)hi)[i] = (u32x2){pack2(h[0], h[1]), pack2(h[2], h[3])};
    ((u32x2*)lo)[i] = (u32x2){pack2(l[0], l[1]), pack2(l[2], l[3])};
}

// ---------------------------------------------------------------------------
// Wq/Wk/Wv [h][k][n] -> transposed hi/lo f16 [h][n][k].
// ---------------------------------------------------------------------------
__global__ __launch_bounds__(256) void wsplit_kernel(
    const float* __restrict__ Wq, const float* __restrict__ Wk, const float* __restrict__ Wv,
    _Float16* __restrict__ qh, _Float16* __restrict__ ql,
    _Float16* __restrict__ kh, _Float16* __restrict__ kl,
    _Float16* __restrict__ vh, _Float16* __restrict__ vl) {
    const int tid = threadIdx.x;
    const int k0 = blockIdx.x * 64, h = blockIdx.y, w = blockIdx.z;
    const float* __restrict__ W = (w == 0) ? Wq : (w == 1) ? Wk : Wv;
    _Float16* __restrict__ dh = (w == 0) ? qh : (w == 1) ? kh : vh;
    _Float16* __restrict__ dl = (w == 0) ? ql : (w == 1) ? kl : vl;
    __shared__ __align__(16) float ws_[64][68];
    #pragma unroll
    for (int it = 0; it < 4; ++it) {
        int idx = it * 256 + tid;
        int r = idx >> 4, c4 = (idx & 15) * 4;
        *(f32x4*)&ws_[r][c4] = *(const f32x4*)&W[((size_t)h * DM + k0 + r) * HD + c4];
    }
    __syncthreads();
    const int n = tid >> 2, kq = (tid & 3) * 16;
    _Float16 hh[16], ll[16];
    #pragma unroll
    for (int j = 0; j < 16; ++j) split1(ws_[kq + j][n], hh[j], ll[j]);
    size_t off = ((size_t)h * HD + n) * DM + k0 + kq;
    *(u32x4*)&dh[off]     = (u32x4){pack2(hh[0],hh[1]),  pack2(hh[2],hh[3]),  pack2(hh[4],hh[5]),  pack2(hh[6],hh[7])};
    *(u32x4*)&dh[off + 8] = (u32x4){pack2(hh[8],hh[9]),  pack2(hh[10],hh[11]),pack2(hh[12],hh[13]),pack2(hh[14],hh[15])};
    *(u32x4*)&dl[off]     = (u32x4){pack2(ll[0],ll[1]),  pack2(ll[2],ll[3]),  pack2(ll[4],ll[5]),  pack2(ll[6],ll[7])};
    *(u32x4*)&dl[off + 8] = (u32x4){pack2(ll[8],ll[9]),  pack2(ll[10],ll[11]),pack2(ll[12],ll[13]),pack2(ll[14],ll[15])};
}

// ---------------------------------------------------------------------------
// Kernel 1: kh = kv@Wk+bk (squared), vh = kv@Wv+bv via 3-term f16-split MFMA;
// rank-64 fp32 reduction into kv_sum/ksum; atomicAdd commit.
// ---------------------------------------------------------------------------
__global__ __launch_bounds__(256, 2) void kv_stats_kernel(
    const _Float16* __restrict__ kv_hi, const _Float16* __restrict__ kv_lo,
    const _Float16* __restrict__ wkt_hi, const _Float16* __restrict__ wkt_lo,
    const _Float16* __restrict__ wvt_hi, const _Float16* __restrict__ wvt_lo,
    const float* __restrict__ bk, const float* __restrict__ bv,
    float* __restrict__ kv_sum, float* __restrict__ ksum)
{
    const int tid = threadIdx.x;
    const int lane = tid & 63, wave = tid >> 6, quad = lane >> 4, l15 = lane & 15;
    const int b = blockIdx.z, h = blockIdx.y;
    const int t0 = blockIdx.x * 64;

    __shared__ __align__(16) _Float16 a_hi[64 * LDH], a_lo[64 * LDH];
    __shared__ __align__(16) _Float16 bkh[64 * LDH], bkl[64 * LDH];
    __shared__ __align__(16) _Float16 bvh[64 * LDH], bvl[64 * LDH];
    __shared__ __align__(16) float khs[64 * 64], vhs[64 * 64];

    const int isV = wave >> 1, mrow0 = (wave & 1) * 32;
    f32x4 acc_h[2][4] = {}, acc_c[2][4] = {};

    const int ar = tid >> 2, ak = (tid & 3) * 8;
    const int bn = tid & 63, bk2 = (tid >> 6) * 8;
    const size_t abase = ((size_t)b * TSEQ + t0 + ar) * DM + ak;
    const size_t bbase = ((size_t)h * HD + bn) * DM + bk2;

    for (int k0 = 0; k0 < DM; k0 += 32) {
        *(u32x4*)&a_hi[ar * LDH + ak]  = *(const u32x4*)&kv_hi[abase + k0];
        *(u32x4*)&a_lo[ar * LDH + ak]  = *(const u32x4*)&kv_lo[abase + k0];
        *(u32x4*)&bkh[bn * LDH + bk2]  = *(const u32x4*)&wkt_hi[bbase + k0];
        *(u32x4*)&bkl[bn * LDH + bk2]  = *(const u32x4*)&wkt_lo[bbase + k0];
        *(u32x4*)&bvh[bn * LDH + bk2]  = *(const u32x4*)&wvt_hi[bbase + k0];
        *(u32x4*)&bvl[bn * LDH + bk2]  = *(const u32x4*)&wvt_lo[bbase + k0];
        __syncthreads();
        f16x8 afh[2], afl[2], bfh[4], bfl[4];
        const _Float16* __restrict__ bh = isV ? bvh : bkh;
        const _Float16* __restrict__ bl = isV ? bvl : bkl;
        #pragma unroll
        for (int mt = 0; mt < 2; ++mt) {
            int row = mrow0 + mt * 16 + l15;
            afh[mt] = *(const f16x8*)&a_hi[row * LDH + quad * 8];
            afl[mt] = *(const f16x8*)&a_lo[row * LDH + quad * 8];
        }
        #pragma unroll
        for (int nt = 0; nt < 4; ++nt) {
            int n = nt * 16 + l15;
            bfh[nt] = *(const f16x8*)&bh[n * LDH + quad * 8];
            bfl[nt] = *(const f16x8*)&bl[n * LDH + quad * 8];
        }
        #pragma unroll
        for (int mt = 0; mt < 2; ++mt)
            #pragma unroll
            for (int nt = 0; nt < 4; ++nt) {
                acc_h[mt][nt] = mfma_f16(afh[mt], bfh[nt], acc_h[mt][nt]);
                acc_c[mt][nt] = mfma_f16(afh[mt], bfl[nt], acc_c[mt][nt]);
                acc_c[mt][nt] = mfma_f16(afl[mt], bfh[nt], acc_c[mt][nt]);
            }
        __syncthreads();
    }

    // epilogue: combine hi+lo/4096 + bias; square kh; waves own disjoint rows
    {
        const float* __restrict__ bias = (isV ? bv : bk) + h * HD;
        float* __restrict__ outs = isV ? vhs : khs;
        float bia[4];
        #pragma unroll
        for (int nt = 0; nt < 4; ++nt) bia[nt] = bias[nt * 16 + l15];
        #pragma unroll
        for (int mt = 0; mt < 2; ++mt)
            #pragma unroll
            for (int nt = 0; nt < 4; ++nt)
                #pragma unroll
                for (int r = 0; r < 4; ++r) {
                    int t = mrow0 + mt * 16 + quad * 4 + r;
                    float v = acc_h[mt][nt][r] + INV_LOSCALE * acc_c[mt][nt][r] + bia[nt];
                    if (!isV) v = v * v;               // wave-uniform branch
                    outs[t * 64 + nt * 16 + l15] = v;
                }
    }
    __syncthreads();

    const int ty = tid >> 4, tx = tid & 15;
    f32x4 akv[4] = {};
    float aks[4] = {0.f, 0.f, 0.f, 0.f};
    #pragma unroll 4
    for (int t = 0; t < 64; ++t) {
        f32x4 kd = *(const f32x4*)&khs[t * 64 + ty * 4];
        f32x4 ve = *(const f32x4*)&vhs[t * 64 + tx * 4];
        #pragma unroll
        for (int i = 0; i < 4; ++i) {
            aks[i] += kd[i];
            akv[i] += kd[i] * ve;
        }
    }
    float* kvp = kv_sum + (size_t)(b * NH + h) * HD * HD;
    #pragma unroll
    for (int i = 0; i < 4; ++i)
        #pragma unroll
        for (int j = 0; j < 4; ++j)
            atomicAdd(&kvp[(ty * 4 + i) * HD + tx * 4 + j], akv[i][j]);
    if (tx == 0) {
        float* ksp = ksum + (b * NH + h) * HD;
        #pragma unroll
        for (int i = 0; i < 4; ++i) atomicAdd(&ksp[ty * 4 + i], aks[i]);
    }
}

// ---------------------------------------------------------------------------
// Kernel 2: qh = q@Wq+bq (f16-split MFMA, A split on the fly); qh2 = qh^2;
// z from registers; attn = z*(qh2@kv_sum) written as hi/lo f16.
// ---------------------------------------------------------------------------
__global__ __launch_bounds__(256, 2) void q_attn_kernel(
    const float* __restrict__ q,
    const _Float16* __restrict__ wqt_hi, const _Float16* __restrict__ wqt_lo,
    const float* __restrict__ bq,
    const float* __restrict__ kv_sum, const float* __restrict__ ksum,
    _Float16* __restrict__ attn_hi, _Float16* __restrict__ attn_lo)
{
    const int tid = threadIdx.x;
    const int lane = tid & 63, wave = tid >> 6, quad = lane >> 4, l15 = lane & 15;
    const int b = blockIdx.z, h = blockIdx.y;
    const int t0 = blockIdx.x * 64;

    __shared__ __align__(16) _Float16 a_hi[64 * LDH], a_lo[64 * LDH];
    __shared__ __align__(16) _Float16 b_hi[64 * LDH], b_lo[64 * LDH];
    __shared__ __align__(16) float qs[64 * 68];
    __shared__ __align__(16) float kvs[64 * 64];
    __shared__ float z_s[64], ks_s[64];

    const float* __restrict__ kvp = kv_sum + (size_t)(b * NH + h) * HD * HD;
    #pragma unroll
    for (int it = 0; it < 4; ++it) {
        int idx = it * 256 + tid;
        int r = idx >> 4, c = (idx & 15) * 4;
        *(f32x4*)&kvs[r * 64 + c] = *(const f32x4*)&kvp[r * HD + c];
    }
    if (tid < 64) ks_s[tid] = ksum[(b * NH + h) * HD + tid];
    __syncthreads();

    const int mrow0 = wave * 16;
    f32x4 acc_h[4] = {}, acc_c[4] = {};
    const int bn = tid & 63, bk2 = (tid >> 6) * 8;
    const size_t bbase = ((size_t)h * HD + bn) * DM + bk2;

    for (int k0 = 0; k0 < DM; k0 += 32) {
        #pragma unroll
        for (int it = 0; it < 2; ++it) {
            int idx = it * 256 + tid;
            int r = idx >> 3, c4 = (idx & 7) * 4;
            f32x4 v = *(const f32x4*)&q[((size_t)b * TSEQ + t0 + r) * DM + k0 + c4];
            _Float16 hh[4], ll[4];
            #pragma unroll
            for (int j = 0; j < 4; ++j) split1(v[j], hh[j], ll[j]);
            *(u32x2*)&a_hi[r * LDH + c4] = (u32x2){pack2(hh[0], hh[1]), pack2(hh[2], hh[3])};
            *(u32x2*)&a_lo[r * LDH + c4] = (u32x2){pack2(ll[0], ll[1]), pack2(ll[2], ll[3])};
        }
        *(u32x4*)&b_hi[bn * LDH + bk2] = *(const u32x4*)&wqt_hi[bbase + k0];
        *(u32x4*)&b_lo[bn * LDH + bk2] = *(const u32x4*)&wqt_lo[bbase + k0];
        __syncthreads();
        f16x8 afh, afl, bfh[4], bfl[4];
        {
            int row = mrow0 + l15;
            afh = *(const f16x8*)&a_hi[row * LDH + quad * 8];
            afl = *(const f16x8*)&a_lo[row * LDH + quad * 8];
        }
        #pragma unroll
        for (int nt = 0; nt < 4; ++nt) {
            int n = nt * 16 + l15;
            bfh[nt] = *(const f16x8*)&b_hi[n * LDH + quad * 8];
            bfl[nt] = *(const f16x8*)&b_lo[n * LDH + quad * 8];
        }
        #pragma unroll
        for (int nt = 0; nt < 4; ++nt) {
            acc_h[nt] = mfma_f16(afh, bfh[nt], acc_h[nt]);
            acc_c[nt] = mfma_f16(afh, bfl[nt], acc_c[nt]);
            acc_c[nt] = mfma_f16(afl, bfh[nt], acc_c[nt]);
        }
        __syncthreads();
    }

    // epilogue: qh2 -> qs; z via shfl over the 16 n-lanes
    {
        const float* __restrict__ bias = bq + h * HD;
        float zp[4] = {0.f, 0.f, 0.f, 0.f};
        #pragma unroll
        for (int nt = 0; nt < 4; ++nt) {
            int d = nt * 16 + l15;
            float bia = bias[d];
            float ks  = ks_s[d];
            #pragma unroll
            for (int r = 0; r < 4; ++r) {
                int t = mrow0 + quad * 4 + r;
                float v = acc_h[nt][r] + INV_LOSCALE * acc_c[nt][r] + bia;
                float v2 = v * v;
                qs[t * 68 + d] = v2;
                zp[r] = fmaf(v2, ks, zp[r]);
            }
        }
        #pragma unroll
        for (int r = 0; r < 4; ++r) {
            float p = zp[r];
            p += __shfl_xor(p, 1);
            p += __shfl_xor(p, 2);
            p += __shfl_xor(p, 4);
            p += __shfl_xor(p, 8);
            if (l15 == 0) z_s[mrow0 + quad * 4 + r] = 1.f / (p + 1e-6f);
        }
    }
    __syncthreads();

    // mini-GEMM: s[t][e] = sum_d qs[t][d]*kvs[d][e]; write attn hi/lo
    const int ty = tid >> 4, tx = tid & 15;
    f32x4 s[4] = {};
    #pragma unroll 4
    for (int d = 0; d < 64; d += 4) {
        f32x4 b0 = *(const f32x4*)&kvs[(d + 0) * 64 + tx * 4];
        f32x4 b1 = *(const f32x4*)&kvs[(d + 1) * 64 + tx * 4];
        f32x4 b2 = *(const f32x4*)&kvs[(d + 2) * 64 + tx * 4];
        f32x4 b3 = *(const f32x4*)&kvs[(d + 3) * 64 + tx * 4];
        #pragma unroll
        for (int i = 0; i < 4; ++i) {
            f32x4 av = *(const f32x4*)&qs[(ty * 4 + i) * 68 + d];
            s[i] += av.x * b0 + av.y * b1 + av.z * b2 + av.w * b3;
        }
    }
    #pragma unroll
    for (int i = 0; i < 4; ++i) {
        int t = ty * 4 + i;
        f32x4 o = s[i] * z_s[t];
        _Float16 hh[4], ll[4];
        #pragma unroll
        for (int j = 0; j < 4; ++j) split1(o[j], hh[j], ll[j]);
        size_t off = ((size_t)b * TSEQ + t0 + t) * DM + h * HD + tx * 4;
        *(u32x2*)&attn_hi[off] = (u32x2){pack2(hh[0], hh[1]), pack2(hh[2], hh[3])};
        *(u32x2*)&attn_lo[off] = (u32x2){pack2(ll[0], ll[1]), pack2(ll[2], ll[3])};
    }
}

// ---------------------------------------------------------------------------
// Kernel 3: out = attn @ Wo^T + bo via f16-split MFMA (both pre-split).
// ---------------------------------------------------------------------------
__global__ __launch_bounds__(256, 2) void out_proj_kernel(
    const _Float16* __restrict__ attn_hi, const _Float16* __restrict__ attn_lo,
    const _Float16* __restrict__ wo_hi, const _Float16* __restrict__ wo_lo,
    const float* __restrict__ bo, float* __restrict__ out)
{
    const int tid = threadIdx.x;
    const int lane = tid & 63, wave = tid >> 6, quad = lane >> 4, l15 = lane & 15;
    const int n0 = blockIdx.x * 64;
    const size_t m0 = (size_t)blockIdx.y * 128;

    __shared__ __align__(16) _Float16 a_hi[128 * LDH], a_lo[128 * LDH];
    __shared__ __align__(16) _Float16 b_hi[64 * LDH], b_lo[64 * LDH];
    __shared__ __align__(16) float cs[128 * 64];

    const int mrow0 = wave * 32;
    f32x4 acc_h[2][4] = {}, acc_c[2][4] = {};
    const int bn = tid & 63, bk2 = (tid >> 6) * 8;
    const size_t bbase = (size_t)(n0 + bn) * DM + bk2;

    for (int k0 = 0; k0 < DM; k0 += 32) {
        #pragma unroll
        for (int it = 0; it < 2; ++it) {
            int idx = it * 256 + tid;
            int r = idx >> 2, kj = (idx & 3) * 8;
            size_t off = (m0 + r) * DM + k0 + kj;
            *(u32x4*)&a_hi[r * LDH + kj] = *(const u32x4*)&attn_hi[off];
            *(u32x4*)&a_lo[r * LDH + kj] = *(const u32x4*)&attn_lo[off];
        }
        *(u32x4*)&b_hi[bn * LDH + bk2] = *(const u32x4*)&wo_hi[bbase + k0];
        *(u32x4*)&b_lo[bn * LDH + bk2] = *(const u32x4*)&wo_lo[bbase + k0];
        __syncthreads();
        f16x8 afh[2], afl[2], bfh[4], bfl[4];
        #pragma unroll
        for (int mt = 0; mt < 2; ++mt) {
            int row = mrow0 + mt * 16 + l15;
            afh[mt] = *(const f16x8*)&a_hi[row * LDH + quad * 8];
            afl[mt] = *(const f16x8*)&a_lo[row * LDH + quad * 8];
        }
        #pragma unroll
        for (int nt = 0; nt < 4; ++nt) {
            int n = nt * 16 + l15;
            bfh[nt] = *(const f16x8*)&b_hi[n * LDH + quad * 8];
            bfl[nt] = *(const f16x8*)&b_lo[n * LDH + quad * 8];
        }
        #pragma unroll
        for (int mt = 0; mt < 2; ++mt)
            #pragma unroll
            for (int nt = 0; nt < 4; ++nt) {
                acc_h[mt][nt] = mfma_f16(afh[mt], bfh[nt], acc_h[mt][nt]);
                acc_c[mt][nt] = mfma_f16(afh[mt], bfl[nt], acc_c[mt][nt]);
                acc_c[mt][nt] = mfma_f16(afl[mt], bfh[nt], acc_c[mt][nt]);
            }
        __syncthreads();
    }

    {
        float bia[4];
        #pragma unroll
        for (int nt = 0; nt < 4; ++nt) bia[nt] = bo[n0 + nt * 16 + l15];
        #pragma unroll
        for (int mt = 0; mt < 2; ++mt)
            #pragma unroll
            for (int nt = 0; nt < 4; ++nt)
                #pragma unroll
                for (int r = 0; r < 4; ++r) {
                    int t = mrow0 + mt * 16 + quad * 4 + r;
                    cs[t * 64 + nt * 16 + l15] =
                        acc_h[mt][nt][r] + INV_LOSCALE * acc_c[mt][nt][r] + bia[nt];
                }
    }
    __syncthreads();
    #pragma unroll
    for (int it = 0; it < 8; ++it) {
        int idx = it * 256 + tid;
        int r = idx >> 4, c = (idx & 15) * 4;
        *(f32x4*)&out[(m0 + r) * DM + n0 + c] = *(const f32x4*)&cs[r * 64 + c];
    }
}

// ---------------------------------------------------------------------------
extern "C" void kernel_launch(void* const* d_in, const int* in_sizes, int n_in,
                              void* d_out, int out_size, void* d_ws, size_t ws_size,
                              hipStream_t stream) {
    const float* q  = (const float*)d_in[0];
    const float* kv = (const float*)d_in[1];
    const float* Wq = (const float*)d_in[2];
    const float* bq = (const float*)d_in[3];
    const float* Wk = (const float*)d_in[4];
    const float* bk = (const float*)d_in[5];
    const float* Wv = (const float*)d_in[6];
    const float* bv = (const float*)d_in[7];
    const float* Wo = (const float*)d_in[8];
    const float* bo = (const float*)d_in[9];
    float* out = (float*)d_out;

    // workspace carve-up (~84.9 MB)
    char* p = (char*)d_ws;
    float* kv_sum = (float*)p;              p += (size_t)BSZ * NH * HD * HD * 4;
    float* ksum   = (float*)p;              p += (size_t)BSZ * NH * HD * 4;
    _Float16* wqt_hi = (_Float16*)p;        p += (size_t)NH * HD * DM * 2;
    _Float16* wqt_lo = (_Float16*)p;        p += (size_t)NH * HD * DM * 2;
    _Float16* wkt_hi = (_Float16*)p;        p += (size_t)NH * HD * DM * 2;
    _Float16* wkt_lo = (_Float16*)p;        p += (size_t)NH * HD * DM * 2;
    _Float16* wvt_hi = (_Float16*)p;        p += (size_t)NH * HD * DM * 2;
    _Float16* wvt_lo = (_Float16*)p;        p += (size_t)NH * HD * DM * 2;
    _Float16* wo_hi  = (_Float16*)p;        p += (size_t)DM * DM * 2;
    _Float16* wo_lo  = (_Float16*)p;        p += (size_t)DM * DM * 2;
    _Float16* buf_hi = (_Float16*)p;        p += (size_t)BT * DM * 2;   // kv splits, then attn
    _Float16* buf_lo = (_Float16*)p;        p += (size_t)BT * DM * 2;

    size_t zero_bytes = ((size_t)BSZ * NH * HD * HD + (size_t)BSZ * NH * HD) * sizeof(float);
    hipMemsetAsync(d_ws, 0, zero_bytes, stream);

    split_kernel<<<(BT * DM / 4) / 256, 256, 0, stream>>>(kv, buf_hi, buf_lo, BT * DM / 4);
    wsplit_kernel<<<dim3(DM / 64, NH, 3), 256, 0, stream>>>(
        Wq, Wk, Wv, wqt_hi, wqt_lo, wkt_hi, wkt_lo, wvt_hi, wvt_lo);
    split_kernel<<<(DM * DM / 4) / 256, 256, 0, stream>>>(Wo, wo_hi, wo_lo, DM * DM / 4);

    kv_stats_kernel<<<dim3(TSEQ / 64, NH, BSZ), 256, 0, stream>>>(
        buf_hi, buf_lo, wkt_hi, wkt_lo, wvt_hi, wvt_lo, bk, bv, kv_sum, ksum);
    q_attn_kernel<<<dim3(TSEQ / 64, NH, BSZ), 256, 0, stream>>>(
        q, wqt_hi, wqt_lo, bq, kv_sum, ksum, buf_hi, buf_lo);   // kv splits dead; reuse as attn
    out_proj_kernel<<<dim3(DM / 64, BT / 128), 256, 0, stream>>>(
        buf_hi, buf_lo, wo_hi, wo_lo, bo, out);
}